// Round 1
// baseline (1166.221 us; speedup 1.0000x reference)
//
#include <hip/hip_runtime.h>
#include <math.h>

#define HW    192
#define PLANE (HW*HW)      // 36864
#define CIN   64
#define COUT  64
#define NB    4
#define NOM   28           // 27 channels padded to 28 (112B stride, 16B aligned)
#define NPIX  (NB*PLANE)   // 147456

// ---------------- Kernel A: offset(18) + mask(9) 3x3 conv, sigmoid fused ----
__global__ __launch_bounds__(256) void koffmask(
    const float* __restrict__ x,
    const float* __restrict__ w_p, const float* __restrict__ b_p,
    const float* __restrict__ w_m, const float* __restrict__ b_m,
    float* __restrict__ om)
{
    int pid = blockIdx.x * 256 + threadIdx.x;   // 0..147455 (exact)
    int b   = pid / PLANE;
    int rem = pid - b * PLANE;
    int h   = rem / HW;
    int w   = rem - h * HW;

    float acc[27];
#pragma unroll
    for (int co = 0; co < 18; ++co) acc[co] = b_p[co];
#pragma unroll
    for (int co = 0; co < 9; ++co)  acc[18 + co] = b_m[co];

    const float* xb = x + (size_t)b * CIN * PLANE;
    for (int ci = 0; ci < CIN; ++ci) {
        const float* pl = xb + ci * PLANE;
        float t[9];
#pragma unroll
        for (int dy = 0; dy < 3; ++dy) {
            int hy = h + dy - 1;
#pragma unroll
            for (int dx = 0; dx < 3; ++dx) {
                int wx = w + dx - 1;
                bool ok = (hy >= 0) && (hy < HW) && (wx >= 0) && (wx < HW);
                t[dy * 3 + dx] = ok ? pl[hy * HW + wx] : 0.0f;
            }
        }
#pragma unroll
        for (int co = 0; co < 18; ++co) {
            const float* wp = w_p + (co * CIN + ci) * 9;   // wave-uniform -> s_load
            float a = acc[co];
#pragma unroll
            for (int k = 0; k < 9; ++k) a += t[k] * wp[k];
            acc[co] = a;
        }
#pragma unroll
        for (int co = 0; co < 9; ++co) {
            const float* wp = w_m + (co * CIN + ci) * 9;
            float a = acc[18 + co];
#pragma unroll
            for (int k = 0; k < 9; ++k) a += t[k] * wp[k];
            acc[18 + co] = a;
        }
    }

    float* o = om + (size_t)pid * NOM;
#pragma unroll
    for (int co = 0; co < 18; ++co) o[co] = acc[co];
#pragma unroll
    for (int co = 0; co < 9; ++co)  o[18 + co] = 1.0f / (1.0f + __expf(-acc[18 + co]));
}

// ---------------- Kernel B: deformable sampling + main GEMM -----------------
// block = 256 threads handles 16 consecutive pixels (same batch, same row)
__global__ __launch_bounds__(256) void kdeform(
    const float* __restrict__ x,
    const float* __restrict__ om,
    const float* __restrict__ wc,     // (64, 64, 9) -> W[o][c*9+n]
    float* __restrict__ outp)         // (B, 64, H, W)
{
    __shared__ int4   sI[9][16];
    __shared__ float4 sG[9][16];
    __shared__ float  sXS[16][580];   // stride 580: (580%32)=4 -> only 2-way alias (free)

    int t    = threadIdx.x;
    int pix0 = blockIdx.x * 16;
    int b    = pix0 / PLANE;
    int rem  = pix0 - b * PLANE;
    int h    = rem / HW;
    int w0   = rem - h * HW;          // multiple of 16

    // ---- phase 1: per-(pixel,tap) gather indices + bilinear*mask weights ----
    if (t < 144) {
        int p = t / 9;
        int n = t - p * 9;
        const float* o = om + (size_t)(pix0 + p) * NOM;
        float offy = o[n], offx = o[9 + n], m = o[18 + n];
        float py = (float)(h + n / 3) + offy;            // padded coords (pad=1 cancels ky-1)
        float px = (float)(w0 + p + (n % 3)) + offx;
        float fy = floorf(py), fx = floorf(px);
        float qy0 = fminf(fmaxf(fy,       0.f), 193.f);
        float qy1 = fminf(fmaxf(fy + 1.f, 0.f), 193.f);
        float qx0 = fminf(fmaxf(fx,       0.f), 193.f);
        float qx1 = fminf(fmaxf(fx + 1.f, 0.f), 193.f);
        float pyc = fminf(fmaxf(py, 0.f), 193.f);
        float pxc = fminf(fmaxf(px, 0.f), 193.f);
        float ay = 1.f + qy0 - pyc, by = 1.f - (qy1 - pyc);
        float ax = 1.f + qx0 - pxc, bx = 1.f - (qx1 - pxc);
        int iy0 = (int)qy0 - 1, iy1 = (int)qy1 - 1;      // back to unpadded image coords
        int ix0 = (int)qx0 - 1, ix1 = (int)qx1 - 1;
        bool vy0 = (iy0 >= 0) && (iy0 < HW), vy1 = (iy1 >= 0) && (iy1 < HW);
        bool vx0 = (ix0 >= 0) && (ix0 < HW), vx1 = (ix1 >= 0) && (ix1 < HW);
        int4 I;
        I.x = (vy0 && vx0) ? iy0 * HW + ix0 : -1;  // lt (qy0,qx0)
        I.y = (vy1 && vx1) ? iy1 * HW + ix1 : -1;  // rb (qy1,qx1)
        I.z = (vy0 && vx1) ? iy0 * HW + ix1 : -1;  // lb (qy0,qx1)
        I.w = (vy1 && vx0) ? iy1 * HW + ix0 : -1;  // rt (qy1,qx0)
        float4 G;
        G.x = ay * ax * m; G.y = by * bx * m; G.z = ay * bx * m; G.w = by * ax * m;
        sI[n][p] = I; sG[n][p] = G;
    }
    __syncthreads();

    // ---- phase 2: sample 16px x 576 (c*9+n) into LDS ----
    {
        int p  = t & 15;          // consecutive lanes -> consecutive pixels (coalesced-ish gathers)
        int kg = t >> 4;          // 16 k-groups
        const float* xb = x + (size_t)b * CIN * PLANE;
        for (int it = 0; it < 36; ++it) {
            int k = it * 16 + kg;             // k = c*9+n
            int c = k / 9;
            int n = k - c * 9;
            int4   I = sI[n][p];
            float4 G = sG[n][p];
            const float* pl = xb + c * PLANE;
            float v = 0.f;
            v += (I.x >= 0) ? G.x * pl[I.x] : 0.f;
            v += (I.y >= 0) ? G.y * pl[I.y] : 0.f;
            v += (I.z >= 0) ? G.z * pl[I.z] : 0.f;
            v += (I.w >= 0) ? G.w * pl[I.w] : 0.f;
            sXS[p][k] = v;
        }
    }
    __syncthreads();

    // ---- phase 3: GEMM  out[p][o] = sum_k xs[p][k] * W[o][k],  K=576 ----
    {
        int p  = t & 15;
        int og = t >> 4;
        float a0 = 0.f, a1 = 0.f, a2 = 0.f, a3 = 0.f;
        const float4* xr  = (const float4*)sXS[p];
        const float4* wp0 = (const float4*)(wc + (size_t)(og     ) * 576);
        const float4* wp1 = (const float4*)(wc + (size_t)(og + 16) * 576);
        const float4* wp2 = (const float4*)(wc + (size_t)(og + 32) * 576);
        const float4* wp3 = (const float4*)(wc + (size_t)(og + 48) * 576);
        for (int k4 = 0; k4 < 144; ++k4) {
            float4 xv = xr[k4];
            float4 v0 = wp0[k4], v1 = wp1[k4], v2 = wp2[k4], v3 = wp3[k4];
            a0 += xv.x * v0.x + xv.y * v0.y + xv.z * v0.z + xv.w * v0.w;
            a1 += xv.x * v1.x + xv.y * v1.y + xv.z * v1.z + xv.w * v1.w;
            a2 += xv.x * v2.x + xv.y * v2.y + xv.z * v2.z + xv.w * v2.w;
            a3 += xv.x * v3.x + xv.y * v3.y + xv.z * v3.z + xv.w * v3.w;
        }
        int hw = rem + p;   // h*192 + w
        outp[((size_t)(b * COUT + og     )) * PLANE + hw] = a0;
        outp[((size_t)(b * COUT + og + 16)) * PLANE + hw] = a1;
        outp[((size_t)(b * COUT + og + 32)) * PLANE + hw] = a2;
        outp[((size_t)(b * COUT + og + 48)) * PLANE + hw] = a3;
    }
}

// ---------------- Kernel C: per-channel batch stats -------------------------
__global__ __launch_bounds__(256) void kstats(
    const float* __restrict__ outp, float* __restrict__ stats)
{
    int o = blockIdx.x;
    int t = threadIdx.x;
    float s = 0.f, s2 = 0.f;
    for (int b = 0; b < NB; ++b) {
        const float4* pl = (const float4*)(outp + ((size_t)(b * COUT + o)) * PLANE);
        for (int i = t; i < PLANE / 4; i += 256) {
            float4 v = pl[i];
            s  += v.x + v.y + v.z + v.w;
            s2 += v.x * v.x + v.y * v.y + v.z * v.z + v.w * v.w;
        }
    }
    __shared__ float rs[256], rs2[256];
    rs[t] = s; rs2[t] = s2;
    __syncthreads();
    for (int st = 128; st > 0; st >>= 1) {
        if (t < st) { rs[t] += rs[t + st]; rs2[t] += rs2[t + st]; }
        __syncthreads();
    }
    if (t == 0) {
        float cnt  = (float)(NB * PLANE);
        float mean = rs[0] / cnt;
        float var  = rs2[0] / cnt - mean * mean;
        stats[o]      = mean;
        stats[64 + o] = rsqrtf(var + 1e-5f);
    }
}

// ---------------- Kernel D: BN + ReLU + 2x2 maxpool -------------------------
__global__ __launch_bounds__(256) void kbnpool(
    const float* __restrict__ outp, const float* __restrict__ stats,
    const float* __restrict__ gamma, const float* __restrict__ beta,
    float* __restrict__ out)
{
    int i = blockIdx.x * 256 + threadIdx.x;   // 0..2359295 (exact)
    int wo  = i % 96;
    int tmp = i / 96;
    int ho  = tmp % 96; tmp /= 96;
    int o   = tmp % 64;
    int b   = tmp / 64;
    float mean = stats[o], rsq = stats[64 + o];
    float g  = gamma[o] * rsq;
    float bt = beta[o] - mean * g;
    const float* pl = outp + ((size_t)(b * COUT + o)) * PLANE + (2 * ho) * HW + 2 * wo;
    float y00 = fmaxf(g * pl[0]      + bt, 0.f);
    float y01 = fmaxf(g * pl[1]      + bt, 0.f);
    float y10 = fmaxf(g * pl[HW]     + bt, 0.f);
    float y11 = fmaxf(g * pl[HW + 1] + bt, 0.f);
    out[i] = fmaxf(fmaxf(y00, y01), fmaxf(y10, y11));
}

// ---------------- launcher --------------------------------------------------
extern "C" void kernel_launch(void* const* d_in, const int* in_sizes, int n_in,
                              void* d_out, int out_size, void* d_ws, size_t ws_size,
                              hipStream_t stream)
{
    const float* x      = (const float*)d_in[0];
    const float* w_p    = (const float*)d_in[1];
    const float* b_p    = (const float*)d_in[2];
    const float* w_m    = (const float*)d_in[3];
    const float* b_m    = (const float*)d_in[4];
    const float* w_conv = (const float*)d_in[5];
    const float* gamma  = (const float*)d_in[6];
    const float* beta   = (const float*)d_in[7];
    float* out = (float*)d_out;

    char* ws = (char*)d_ws;
    float* om    = (float*)ws;                                  // 147456*28*4 = 16515072 B
    float* outp  = (float*)(ws + 16515072);                     // 4*64*36864*4 = 37748736 B
    float* stats = (float*)(ws + 16515072 + 37748736);          // 128 floats

    koffmask<<<NPIX / 256, 256, 0, stream>>>(x, w_p, b_p, w_m, b_m, om);
    kdeform<<<NPIX / 16, 256, 0, stream>>>(x, om, w_conv, outp);
    kstats<<<64, 256, 0, stream>>>(outp, stats);
    kbnpool<<<(NB * COUT * 96 * 96) / 256, 256, 0, stream>>>(outp, stats, gamma, beta, out);
}

// Round 2
// 536.830 us; speedup vs baseline: 2.1724x; 2.1724x over previous
//
#include <hip/hip_runtime.h>
#include <hip/hip_bf16.h>
#include <math.h>

#define HW    192
#define PLANE (HW*HW)      // 36864
#define CIN   64
#define COUT  64
#define NB    4
#define NOM   28           // 27 channels padded to 28 (112B stride, 16B aligned)
#define NPIX  (NB*PLANE)   // 147456

typedef __attribute__((ext_vector_type(8))) short bf16x8;
typedef __attribute__((ext_vector_type(4))) float f32x4;

static __device__ __forceinline__ ushort f2bf(float f) {
    __hip_bfloat16 h = __float2bfloat16(f);
    return __builtin_bit_cast(ushort, h);
}

// ---------------- Kernel A: offset(18) + mask(9) 3x3 conv, sigmoid fused ----
__global__ __launch_bounds__(256) void koffmask(
    const float* __restrict__ x,
    const float* __restrict__ w_p, const float* __restrict__ b_p,
    const float* __restrict__ w_m, const float* __restrict__ b_m,
    float* __restrict__ om)
{
    int pid = blockIdx.x * 256 + threadIdx.x;   // 0..147455 (exact)
    int b   = pid / PLANE;
    int rem = pid - b * PLANE;
    int h   = rem / HW;
    int w   = rem - h * HW;

    float acc[27];
#pragma unroll
    for (int co = 0; co < 18; ++co) acc[co] = b_p[co];
#pragma unroll
    for (int co = 0; co < 9; ++co)  acc[18 + co] = b_m[co];

    const float* xb = x + (size_t)b * CIN * PLANE;
    for (int ci = 0; ci < CIN; ++ci) {
        const float* pl = xb + ci * PLANE;
        float t[9];
#pragma unroll
        for (int dy = 0; dy < 3; ++dy) {
            int hy = h + dy - 1;
#pragma unroll
            for (int dx = 0; dx < 3; ++dx) {
                int wx = w + dx - 1;
                bool ok = (hy >= 0) && (hy < HW) && (wx >= 0) && (wx < HW);
                t[dy * 3 + dx] = ok ? pl[hy * HW + wx] : 0.0f;
            }
        }
#pragma unroll
        for (int co = 0; co < 18; ++co) {
            const float* wp = w_p + (co * CIN + ci) * 9;   // wave-uniform -> s_load
            float a = acc[co];
#pragma unroll
            for (int k = 0; k < 9; ++k) a += t[k] * wp[k];
            acc[co] = a;
        }
#pragma unroll
        for (int co = 0; co < 9; ++co) {
            const float* wp = w_m + (co * CIN + ci) * 9;
            float a = acc[18 + co];
#pragma unroll
            for (int k = 0; k < 9; ++k) a += t[k] * wp[k];
            acc[18 + co] = a;
        }
    }

    float* o = om + (size_t)pid * NOM;
#pragma unroll
    for (int co = 0; co < 18; ++co) o[co] = acc[co];
#pragma unroll
    for (int co = 0; co < 9; ++co)  o[18 + co] = 1.0f / (1.0f + __expf(-acc[18 + co]));
}

// ---------------- Kernel P: pre-convert weights to bf16 B-fragment order ----
// wbf[((og*18+chunk)*64 + lane)*8 + j] = bf16(W[og*16 + (lane&15)][chunk*32 + (lane>>4)*8 + j])
__global__ __launch_bounds__(256) void kprep(
    const float* __restrict__ wc, ushort* __restrict__ wbf)
{
    int i = blockIdx.x * 256 + threadIdx.x;  // 0..4607 exact (4 og * 18 chunk * 64 lane)
    int lane  = i & 63;
    int rc    = i >> 6;           // 0..71
    int chunk = rc % 18;
    int og    = rc / 18;
    int o  = og * 16 + (lane & 15);
    int k0 = chunk * 32 + (lane >> 4) * 8;
    ushort v[8];
#pragma unroll
    for (int j = 0; j < 8; ++j) v[j] = f2bf(wc[o * 576 + k0 + j]);
    ((uint4*)wbf)[i] = *(uint4*)v;   // coalesced 16B store
}

// ---------------- Kernel B: deformable sampling + MFMA GEMM -----------------
// block = 256 threads (4 waves) handles 16 consecutive pixels (same batch/row)
__global__ __launch_bounds__(256, 6) void kdeform(
    const float* __restrict__ x,
    const float* __restrict__ om,
    const ushort* __restrict__ wbf,   // bf16 weights in B-fragment order
    float* __restrict__ outp)         // (B, 64, H, W)
{
    __shared__ int4   sI[9][16];          // 2304 B
    __shared__ float4 sG[9][16];          // 2304 B
    __shared__ ushort sXF[18 * 64 * 8];   // 18432 B: x_s bf16 in A/B-fragment order

    int t    = threadIdx.x;
    int pix0 = blockIdx.x * 16;
    int b    = pix0 / PLANE;
    int rem  = pix0 - b * PLANE;
    int h    = rem / HW;
    int w0   = rem - h * HW;          // multiple of 16

    // ---- phase 1: per-(pixel,tap) gather indices + bilinear*mask weights ----
    if (t < 144) {
        int p = t / 9;
        int n = t - p * 9;
        const float* o = om + (size_t)(pix0 + p) * NOM;
        float offy = o[n], offx = o[9 + n], m = o[18 + n];
        float py = (float)(h + n / 3) + offy;            // padded coords (pad=1 cancels ky-1)
        float px = (float)(w0 + p + (n % 3)) + offx;
        float fy = floorf(py), fx = floorf(px);
        float qy0 = fminf(fmaxf(fy,       0.f), 193.f);
        float qy1 = fminf(fmaxf(fy + 1.f, 0.f), 193.f);
        float qx0 = fminf(fmaxf(fx,       0.f), 193.f);
        float qx1 = fminf(fmaxf(fx + 1.f, 0.f), 193.f);
        float pyc = fminf(fmaxf(py, 0.f), 193.f);
        float pxc = fminf(fmaxf(px, 0.f), 193.f);
        float ay = 1.f + qy0 - pyc, by = 1.f - (qy1 - pyc);
        float ax = 1.f + qx0 - pxc, bx = 1.f - (qx1 - pxc);
        int iy0 = (int)qy0 - 1, iy1 = (int)qy1 - 1;      // back to unpadded image coords
        int ix0 = (int)qx0 - 1, ix1 = (int)qx1 - 1;
        bool vy0 = (iy0 >= 0) && (iy0 < HW), vy1 = (iy1 >= 0) && (iy1 < HW);
        bool vx0 = (ix0 >= 0) && (ix0 < HW), vx1 = (ix1 >= 0) && (ix1 < HW);
        int4 I;
        I.x = (vy0 && vx0) ? iy0 * HW + ix0 : -1;
        I.y = (vy1 && vx1) ? iy1 * HW + ix1 : -1;
        I.z = (vy0 && vx1) ? iy0 * HW + ix1 : -1;
        I.w = (vy1 && vx0) ? iy1 * HW + ix0 : -1;
        float4 G;
        G.x = ay * ax * m; G.y = by * bx * m; G.z = ay * bx * m; G.w = by * ax * m;
        sI[n][p] = I; sG[n][p] = G;
    }
    __syncthreads();

    // ---- phase 2: sample, convert to bf16, write LDS in fragment order ----
    {
        int p   = t & 15;
        int q16 = t >> 4;
        const float* xb = x + (size_t)b * CIN * PLANE;
#pragma unroll
        for (int it = 0; it < 9; ++it) {
            int k0 = 4 * q16 + 64 * it;     // 4-aligned, covers 0..572
            ushort pk[4];
#pragma unroll
            for (int jj = 0; jj < 4; ++jj) {
                int k = k0 + jj;
                int c = (k * 7282) >> 16;   // k/9 for k < 590
                int n = k - c * 9;
                int4   I = sI[n][p];
                float4 G = sG[n][p];
                const float* pl = xb + c * PLANE;
                float v = 0.f;
                v += (I.x >= 0) ? G.x * pl[I.x] : 0.f;
                v += (I.y >= 0) ? G.y * pl[I.y] : 0.f;
                v += (I.z >= 0) ? G.z * pl[I.z] : 0.f;
                v += (I.w >= 0) ? G.w * pl[I.w] : 0.f;
                pk[jj] = f2bf(v);
            }
            int chunk = k0 >> 5;
            int kk0   = k0 & 31;
            int e = (chunk * 64 + (kk0 >> 3) * 16 + p) * 8 + (kk0 & 7);
            *(uint2*)&sXF[e] = *(const uint2*)pk;   // 8B fragment-order write
        }
    }
    __syncthreads();

    // ---- phase 3: MFMA GEMM. A = weights (M=16 outs), B = x_s (N=16 pixels) ----
    {
        int lane = t & 63;
        int og   = t >> 6;      // wave -> output group of 16
        f32x4 acc = {0.f, 0.f, 0.f, 0.f};
#pragma unroll
        for (int chunk = 0; chunk < 18; ++chunk) {
            bf16x8 a = *(const bf16x8*)&wbf[((og * 18 + chunk) * 64 + lane) * 8];
            bf16x8 bb = *(const bf16x8*)&sXF[(chunk * 64 + lane) * 8];
            acc = __builtin_amdgcn_mfma_f32_16x16x32_bf16(a, bb, acc, 0, 0, 0);
        }
        // D: col(lane&15) = pixel, row((lane>>4)*4+reg) = output within group
        int col  = lane & 15;
        int row0 = (lane >> 4) * 4;
        float* ob = outp + ((size_t)(b * COUT + og * 16 + row0)) * PLANE + rem + col;
        ob[0]                 = acc[0];
        ob[(size_t)PLANE]     = acc[1];
        ob[2 * (size_t)PLANE] = acc[2];
        ob[3 * (size_t)PLANE] = acc[3];
    }
}

// ---------------- Kernel C: per-channel batch stats -------------------------
__global__ __launch_bounds__(256) void kstats(
    const float* __restrict__ outp, float* __restrict__ stats)
{
    int o = blockIdx.x;
    int t = threadIdx.x;
    float s = 0.f, s2 = 0.f;
    for (int b = 0; b < NB; ++b) {
        const float4* pl = (const float4*)(outp + ((size_t)(b * COUT + o)) * PLANE);
        for (int i = t; i < PLANE / 4; i += 256) {
            float4 v = pl[i];
            s  += v.x + v.y + v.z + v.w;
            s2 += v.x * v.x + v.y * v.y + v.z * v.z + v.w * v.w;
        }
    }
    __shared__ float rs[256], rs2[256];
    rs[t] = s; rs2[t] = s2;
    __syncthreads();
    for (int st = 128; st > 0; st >>= 1) {
        if (t < st) { rs[t] += rs[t + st]; rs2[t] += rs2[t + st]; }
        __syncthreads();
    }
    if (t == 0) {
        float cnt  = (float)(NB * PLANE);
        float mean = rs[0] / cnt;
        float var  = rs2[0] / cnt - mean * mean;
        stats[o]      = mean;
        stats[64 + o] = rsqrtf(var + 1e-5f);
    }
}

// ---------------- Kernel D: BN + ReLU + 2x2 maxpool -------------------------
__global__ __launch_bounds__(256) void kbnpool(
    const float* __restrict__ outp, const float* __restrict__ stats,
    const float* __restrict__ gamma, const float* __restrict__ beta,
    float* __restrict__ out)
{
    int i = blockIdx.x * 256 + threadIdx.x;   // 0..2359295 (exact)
    int wo  = i % 96;
    int tmp = i / 96;
    int ho  = tmp % 96; tmp /= 96;
    int o   = tmp % 64;
    int b   = tmp / 64;
    float mean = stats[o], rsq = stats[64 + o];
    float g  = gamma[o] * rsq;
    float bt = beta[o] - mean * g;
    const float* pl = outp + ((size_t)(b * COUT + o)) * PLANE + (2 * ho) * HW + 2 * wo;
    float y00 = fmaxf(g * pl[0]      + bt, 0.f);
    float y01 = fmaxf(g * pl[1]      + bt, 0.f);
    float y10 = fmaxf(g * pl[HW]     + bt, 0.f);
    float y11 = fmaxf(g * pl[HW + 1] + bt, 0.f);
    out[i] = fmaxf(fmaxf(y00, y01), fmaxf(y10, y11));
}

// ---------------- launcher --------------------------------------------------
extern "C" void kernel_launch(void* const* d_in, const int* in_sizes, int n_in,
                              void* d_out, int out_size, void* d_ws, size_t ws_size,
                              hipStream_t stream)
{
    const float* x      = (const float*)d_in[0];
    const float* w_p    = (const float*)d_in[1];
    const float* b_p    = (const float*)d_in[2];
    const float* w_m    = (const float*)d_in[3];
    const float* b_m    = (const float*)d_in[4];
    const float* w_conv = (const float*)d_in[5];
    const float* gamma  = (const float*)d_in[6];
    const float* beta   = (const float*)d_in[7];
    float* out = (float*)d_out;

    char* ws = (char*)d_ws;
    float*  om    = (float*)ws;                              // 16515072 B
    float*  outp  = (float*)(ws + 16515072);                 // 37748736 B
    float*  stats = (float*)(ws + 16515072 + 37748736);      // 512 B
    ushort* wbf   = (ushort*)(ws + 16515072 + 37748736 + 512); // 73728 B

    koffmask<<<NPIX / 256, 256, 0, stream>>>(x, w_p, b_p, w_m, b_m, om);
    kprep<<<18, 256, 0, stream>>>(w_conv, wbf);
    kdeform<<<NPIX / 16, 256, 0, stream>>>(x, om, wbf, outp);
    kstats<<<64, 256, 0, stream>>>(outp, stats);
    kbnpool<<<(NB * COUT * 96 * 96) / 256, 256, 0, stream>>>(outp, stats, gamma, beta, out);
}

// Round 3
// 385.263 us; speedup vs baseline: 3.0271x; 1.3934x over previous
//
#include <hip/hip_runtime.h>
#include <hip/hip_bf16.h>
#include <math.h>

#define HW     192
#define PLANE  (HW*HW)        // 36864
#define CIN    64
#define COUT   64
#define NB     4
#define NPIX   (NB*PLANE)     // 147456
#define H2     194
#define W2     200
#define PPLANE (H2*W2)        // 38800 ushorts per padded plane

typedef __attribute__((ext_vector_type(8))) short bf16x8;
typedef __attribute__((ext_vector_type(4))) float f32x4;

static __device__ __forceinline__ ushort f2bf(float f) {
    __hip_bfloat16 h = __float2bfloat16(f);
    return __builtin_bit_cast(ushort, h);
}
static __device__ __forceinline__ float bf2f(ushort u) {
    unsigned v = ((unsigned)u) << 16;
    return __builtin_bit_cast(float, v);
}

// ---------------- Kernel 0: zero-padded bf16 copy of x ----------------------
// xp[b][c][y][xc], y in 0..193, xc in 0..199; data at [1..192][1..192]
__global__ __launch_bounds__(256) void kpad(
    const float* __restrict__ x, ushort* __restrict__ xp)
{
    int i  = blockIdx.x * 256 + threadIdx.x;   // 0..9,932,799 exact
    int xc = i % W2;
    int t2 = i / W2;
    int y  = t2 % H2;
    int bc = t2 / H2;                           // 0..255
    float v = 0.f;
    if (y >= 1 && y <= HW && xc >= 1 && xc <= HW)
        v = x[(size_t)bc * PLANE + (y - 1) * HW + (xc - 1)];
    xp[i] = f2bf(v);
}

// ---------------- Kernel P: weights -> bf16 MFMA A-fragment order -----------
// main: wbf[((og*18+chunk)*64+lane)*8+j] = W[og*16+(lane&15)][chunk*32+(lane>>4)*8+j]
// offmask: womf same layout, 32 rows: 0..17 = w_p, 18..26 = w_m, 27..31 = 0
__global__ __launch_bounds__(256) void kprep(
    const float* __restrict__ wc, const float* __restrict__ w_p,
    const float* __restrict__ w_m,
    ushort* __restrict__ wbf, ushort* __restrict__ womf)
{
    int i = blockIdx.x * 256 + threadIdx.x;    // grid 27*256 = 6912
    if (i < 4608) {
        int lane  = i & 63;
        int rc    = i >> 6;
        int chunk = rc % 18;
        int og    = rc / 18;
        int o  = og * 16 + (lane & 15);
        int k0 = chunk * 32 + (lane >> 4) * 8;
        ushort v[8];
#pragma unroll
        for (int j = 0; j < 8; ++j) v[j] = f2bf(wc[o * 576 + k0 + j]);
        ((uint4*)wbf)[i] = *(uint4*)v;
    } else if (i < 4608 + 2304) {
        int ii    = i - 4608;
        int lane  = ii & 63;
        int rc    = ii >> 6;                   // 0..35
        int chunk = rc % 18;
        int og    = rc / 18;                   // 0..1
        int co = og * 16 + (lane & 15);
        int k0 = chunk * 32 + (lane >> 4) * 8;
        ushort v[8];
#pragma unroll
        for (int j = 0; j < 8; ++j) {
            float w = 0.f;
            if (co < 18)      w = w_p[co * 576 + k0 + j];
            else if (co < 27) w = w_m[(co - 18) * 576 + k0 + j];
            v[j] = f2bf(w);
        }
        ((uint4*)womf)[ii] = *(uint4*)v;
    }
}

// ---------------- Kernel B: offsets (MFMA) + sampling + main GEMM (MFMA) ----
// block = 256 threads (4 waves) handles 16 consecutive pixels (same batch/row)
__global__ __launch_bounds__(256, 6) void kdeform(
    const ushort* __restrict__ xp,
    const ushort* __restrict__ wbf,
    const ushort* __restrict__ womf,
    const float* __restrict__ b_p, const float* __restrict__ b_m,
    ushort* __restrict__ outp)         // (B, 64, H, W) bf16
{
    __shared__ ushort sXF[9216];       // 18432 B: fragment-order tile (im2col, then x_s)
    __shared__ float4 sG[9][16];       // 2304 B: bilinear*mask weights
    __shared__ int4   sO[9][16];       // 2304 B: 4 gather byte-offsets
    __shared__ float  sOM[32][16];     // 2048 B: offset-conv result (co, pixel)

    int t    = threadIdx.x;
    int pix0 = blockIdx.x * 16;
    int b    = pix0 / PLANE;
    int rem  = pix0 - b * PLANE;
    int h    = rem / HW;
    int w0   = rem - h * HW;           // multiple of 16
    int p    = t & 15;
    int q16  = t >> 4;

    const ushort* xpb = xp + (size_t)b * CIN * PPLANE;

    // ---- phase A: stage im2col tile (bf16) in fragment order ----
#pragma unroll
    for (int it = 0; it < 9; ++it) {
        int k0 = 4 * q16 + 64 * it;
        ushort pk[4];
#pragma unroll
        for (int jj = 0; jj < 4; ++jj) {
            int k = k0 + jj;
            int c = (k * 7282) >> 16;          // k/9
            int n = k - c * 9;
            int dy = n / 3, dx = n - dy * 3;
            pk[jj] = xpb[c * PPLANE + (h + dy) * W2 + (w0 + p + dx)];
        }
        int chunk = k0 >> 5, kk0 = k0 & 31;
        int e = (chunk * 64 + (kk0 >> 3) * 16 + p) * 8 + (kk0 & 7);
        *(uint2*)&sXF[e] = *(const uint2*)pk;
    }
    __syncthreads();

    // ---- phase B: offset+mask conv via MFMA (waves 0,1 -> 32 rows) ----
    if (t < 128) {
        int lane = t & 63;
        int og   = t >> 6;
        f32x4 acc = {0.f, 0.f, 0.f, 0.f};
#pragma unroll
        for (int chunk = 0; chunk < 18; ++chunk) {
            bf16x8 a  = *(const bf16x8*)&womf[((og * 18 + chunk) * 64 + lane) * 8];
            bf16x8 bb = *(const bf16x8*)&sXF[(chunk * 64 + lane) * 8];
            acc = __builtin_amdgcn_mfma_f32_16x16x32_bf16(a, bb, acc, 0, 0, 0);
        }
        int col = lane & 15, row0 = (lane >> 4) * 4;
#pragma unroll
        for (int r = 0; r < 4; ++r) sOM[og * 16 + row0 + r][col] = acc[r];
    }
    __syncthreads();

    // ---- phase C: per-(pixel,tap) gather offsets + bilinear*mask weights ----
    if (t < 144) {
        int pp = t & 15, n = t >> 4;           // n in 0..8
        float offy = sOM[n][pp]      + b_p[n];
        float offx = sOM[9 + n][pp]  + b_p[9 + n];
        float mr   = sOM[18 + n][pp] + b_m[n];
        float m = 1.f / (1.f + __expf(-mr));
        int dy = n / 3, dx = n - dy * 3;
        float py = (float)(h + dy) + offy;         // padded coords
        float px = (float)(w0 + pp + dx) + offx;
        float fy = floorf(py), fx = floorf(px);
        float qy0 = fminf(fmaxf(fy,       0.f), 193.f);
        float qy1 = fminf(fmaxf(fy + 1.f, 0.f), 193.f);
        float qx0 = fminf(fmaxf(fx,       0.f), 193.f);
        float qx1 = fminf(fmaxf(fx + 1.f, 0.f), 193.f);
        float pyc = fminf(fmaxf(py, 0.f), 193.f);
        float pxc = fminf(fmaxf(px, 0.f), 193.f);
        float ay = 1.f + qy0 - pyc, by = 1.f - (qy1 - pyc);
        float ax = 1.f + qx0 - pxc, bx = 1.f - (qx1 - pxc);
        int A0 = ((int)qy0 * W2 + (int)qx0) * 2;   // byte offsets into bf16 plane
        int A1 = ((int)qy1 * W2 + (int)qx0) * 2;
        int xs = ((int)qx1 - (int)qx0) * 2;        // 0 or 2
        sO[n][pp] = make_int4(A0, A0 + xs, A1, A1 + xs);
        sG[n][pp] = make_float4(ay * ax * m, ay * bx * m, by * ax * m, by * bx * m);
    }
    __syncthreads();

    // ---- phase D: deformable sampling -> overwrite sXF with x_s (bf16) ----
    {
        // thread (p, j): channels c = 4j..4j+3, all 9 taps
        const char* pc0 = (const char*)(xpb + (4 * q16) * PPLANE);
#pragma unroll
        for (int n = 0; n < 9; ++n) {
            int4   O = sO[n][p];
            float4 G = sG[n][p];
#pragma unroll
            for (int ci = 0; ci < 4; ++ci) {
                const char* pc = pc0 + ci * (PPLANE * 2);
                float v = G.x * bf2f(*(const ushort*)(pc + O.x))
                        + G.y * bf2f(*(const ushort*)(pc + O.y))
                        + G.z * bf2f(*(const ushort*)(pc + O.z))
                        + G.w * bf2f(*(const ushort*)(pc + O.w));
                int k = (4 * q16 + ci) * 9 + n;
                sXF[(k >> 5) * 512 + ((k & 31) >> 3) * 128 + p * 8 + (k & 7)] = f2bf(v);
            }
        }
    }
    __syncthreads();

    // ---- phase E: main MFMA GEMM, store bf16 ----
    {
        int lane = t & 63;
        int og   = t >> 6;
        f32x4 acc = {0.f, 0.f, 0.f, 0.f};
#pragma unroll
        for (int chunk = 0; chunk < 18; ++chunk) {
            bf16x8 a  = *(const bf16x8*)&wbf[((og * 18 + chunk) * 64 + lane) * 8];
            bf16x8 bb = *(const bf16x8*)&sXF[(chunk * 64 + lane) * 8];
            acc = __builtin_amdgcn_mfma_f32_16x16x32_bf16(a, bb, acc, 0, 0, 0);
        }
        int col = lane & 15, row0 = (lane >> 4) * 4;
        ushort* ob = outp + ((size_t)(b * COUT + og * 16 + row0)) * PLANE + rem + col;
        ob[0]                 = f2bf(acc[0]);
        ob[(size_t)PLANE]     = f2bf(acc[1]);
        ob[2 * (size_t)PLANE] = f2bf(acc[2]);
        ob[3 * (size_t)PLANE] = f2bf(acc[3]);
    }
}

// ---------------- Kernel C: per-channel batch stats (bf16 in) ---------------
__global__ __launch_bounds__(256) void kstats(
    const ushort* __restrict__ outp, float* __restrict__ stats)
{
    int o = blockIdx.x;
    int t = threadIdx.x;
    float s = 0.f, s2 = 0.f;
    for (int b = 0; b < NB; ++b) {
        const uint4* pl = (const uint4*)(outp + ((size_t)(b * COUT + o)) * PLANE);
        for (int i = t; i < PLANE / 8; i += 256) {   // 18 iters
            uint4 v = pl[i];
            unsigned ua[4] = {v.x, v.y, v.z, v.w};
#pragma unroll
            for (int j = 0; j < 4; ++j) {
                float lo = __builtin_bit_cast(float, ua[j] << 16);
                float hi = __builtin_bit_cast(float, ua[j] & 0xffff0000u);
                s  += lo + hi;
                s2 += lo * lo + hi * hi;
            }
        }
    }
    __shared__ float rs[256], rs2[256];
    rs[t] = s; rs2[t] = s2;
    __syncthreads();
    for (int st = 128; st > 0; st >>= 1) {
        if (t < st) { rs[t] += rs[t + st]; rs2[t] += rs2[t + st]; }
        __syncthreads();
    }
    if (t == 0) {
        float cnt  = (float)(NB * PLANE);
        float mean = rs[0] / cnt;
        float var  = rs2[0] / cnt - mean * mean;
        stats[o]      = mean;
        stats[64 + o] = rsqrtf(var + 1e-5f);
    }
}

// ---------------- Kernel D: BN + ReLU + 2x2 maxpool (bf16 in, f32 out) ------
__global__ __launch_bounds__(256) void kbnpool(
    const ushort* __restrict__ outp, const float* __restrict__ stats,
    const float* __restrict__ gamma, const float* __restrict__ beta,
    float* __restrict__ out)
{
    int i = blockIdx.x * 256 + threadIdx.x;   // 0..2359295 exact
    int wo  = i % 96;
    int tmp = i / 96;
    int ho  = tmp % 96; tmp /= 96;
    int o   = tmp % 64;
    int b   = tmp / 64;
    float mean = stats[o], rsq = stats[64 + o];
    float g  = gamma[o] * rsq;
    float bt = beta[o] - mean * g;
    const ushort* pl = outp + ((size_t)(b * COUT + o)) * PLANE + (2 * ho) * HW + 2 * wo;
    unsigned u01 = *(const unsigned*)pl;
    unsigned u23 = *(const unsigned*)(pl + HW);
    float y00 = fmaxf(g * __builtin_bit_cast(float, u01 << 16)         + bt, 0.f);
    float y01 = fmaxf(g * __builtin_bit_cast(float, u01 & 0xffff0000u) + bt, 0.f);
    float y10 = fmaxf(g * __builtin_bit_cast(float, u23 << 16)         + bt, 0.f);
    float y11 = fmaxf(g * __builtin_bit_cast(float, u23 & 0xffff0000u) + bt, 0.f);
    out[i] = fmaxf(fmaxf(y00, y01), fmaxf(y10, y11));
}

// ---------------- launcher --------------------------------------------------
extern "C" void kernel_launch(void* const* d_in, const int* in_sizes, int n_in,
                              void* d_out, int out_size, void* d_ws, size_t ws_size,
                              hipStream_t stream)
{
    const float* x      = (const float*)d_in[0];
    const float* w_p    = (const float*)d_in[1];
    const float* b_p    = (const float*)d_in[2];
    const float* w_m    = (const float*)d_in[3];
    const float* b_m    = (const float*)d_in[4];
    const float* w_conv = (const float*)d_in[5];
    const float* gamma  = (const float*)d_in[6];
    const float* beta   = (const float*)d_in[7];
    float* out = (float*)d_out;

    char* ws = (char*)d_ws;
    ushort* xp    = (ushort*)ws;                    // 19,865,600 B
    ushort* outp  = (ushort*)(ws + 19865600);       // 18,874,368 B
    float*  stats = (float*)(ws + 38739968);        // 512 B
    ushort* wbf   = (ushort*)(ws + 38740480);       // 73,728 B
    ushort* womf  = (ushort*)(ws + 38814208);       // 36,864 B

    kpad<<<38800, 256, 0, stream>>>(x, xp);
    kprep<<<27, 256, 0, stream>>>(w_conv, w_p, w_m, wbf, womf);
    kdeform<<<NPIX / 16, 256, 0, stream>>>(xp, wbf, womf, b_p, b_m, outp);
    kstats<<<64, 256, 0, stream>>>(outp, stats);
    kbnpool<<<(NB * COUT * 96 * 96) / 256, 256, 0, stream>>>(outp, stats, gamma, beta, out);
}